// Round 4
// baseline (1387.576 us; speedup 1.0000x reference)
//
#include <hip/hip_runtime.h>
#include <math.h>

#define B_    4
#define HW_   4800
#define K_    8
#define IMGD  192
#define PTD   128
#define NH_   6
#define DH_   64
#define INNER 384
#define KVIN  154     // PTD + 26 pos dims
#define QT    8       // queries per block (kernel 2)
#define NJ    64      // QT * K_
#define HK0   80      // X half 0: f3 cols 0..79
#define HK1   74      // X half 1: f3 cols 80..127 + 26 pos
#define XST   81      // s_X / s_regB stride (odd -> 2-way-max banks)

// ---------------------------------------------------------------------------
// Kernel 1: brute-force kNN. One 64-lane wave per query.
// Distance replicates the reference's f32 BLAS-path arithmetic:
//   d2 = (sqq + sqp) - 2*dot,  dot = fma(qy,py, round(qx*px))   [verified r3]
// ---------------------------------------------------------------------------
__global__ __launch_bounds__(256) void knn_kernel(
    const float* __restrict__ proj_uv,   // [B][HW][2]
    const float* __restrict__ img_uv,    // [HW][2]
    int* __restrict__ idx_out)           // [B][HW][K]
{
#pragma clang fp contract(off)
  __shared__ float s_px[HW_];
  __shared__ float s_py[HW_];
  __shared__ float s_cd[256][K_];
  __shared__ int   s_ci[256][K_];

  const int tid  = threadIdx.x;
  const int wave = tid >> 6;
  const int lane = tid & 63;
  const int blk  = blockIdx.x;               // 0..4799
  const int b    = blk / (HW_ / 4);
  const int q    = (blk % (HW_ / 4)) * 4 + wave;

  const float2* pv = reinterpret_cast<const float2*>(proj_uv + (size_t)b * HW_ * 2);
  for (int i = tid; i < HW_; i += 256) {
    float2 p = pv[i];
    s_px[i] = p.x; s_py[i] = p.y;
  }
  __syncthreads();

  const float qx = img_uv[q * 2 + 0];
  const float qy = img_uv[q * 2 + 1];
  const float sqq = qx * qx + qy * qy;       // square-then-sum, no fma (pragma)

  float dist[K_];
  int   ind[K_];
#pragma unroll
  for (int s = 0; s < K_; ++s) { dist[s] = 3.4e38f; ind[s] = 0x7fffffff; }

  for (int n = lane; n < HW_; n += 64) {
    const float px = s_px[n], py = s_py[n];
    const float sqp = px * px + py * py;     // f32 no fma
    const float dot = fmaf(qy, py, qx * px); // BLAS K=2: fma ascending k
    const float d   = (sqq + sqp) - 2.0f * dot;
    if (d < dist[K_ - 1]) {
      bool placed = false;
#pragma unroll
      for (int s = K_ - 1; s >= 1; --s) {
        if (!placed) {
          if (d < dist[s - 1]) { dist[s] = dist[s - 1]; ind[s] = ind[s - 1]; }
          else                 { dist[s] = d; ind[s] = n; placed = true; }
        }
      }
      if (!placed) { dist[0] = d; ind[0] = n; }
    }
  }

#pragma unroll
  for (int s = 0; s < K_; ++s) { s_cd[tid][s] = dist[s]; s_ci[tid][s] = ind[s]; }

  int p = 0;
#pragma unroll
  for (int r = 0; r < K_; ++r) {
    float hd = (p < K_) ? s_cd[tid][p] : 3.4e38f;
    int   hi = (p < K_) ? s_ci[tid][p] : 0x7fffffff;
    float bd = hd; int bi = hi;
#pragma unroll
    for (int m = 1; m < 64; m <<= 1) {
      float od = __shfl_xor(bd, m);
      int   oi = __shfl_xor(bi, m);
      if (od < bd || (od == bd && oi < bi)) { bd = od; bi = oi; }
    }
    if (hd == bd && hi == bi) p++;
    if (lane == r) idx_out[((size_t)b * HW_ + q) * K_ + r] = bi;
  }
}

// ---------------------------------------------------------------------------
// Kernel 2: fused pipeline, K-dim split into 2 halves so LDS fits 3 blocks/CU.
// ---------------------------------------------------------------------------
__global__ __launch_bounds__(256, 3) void fused_kernel(
    const float* __restrict__ feat_2d,
    const float* __restrict__ feat_3d,
    const float* __restrict__ img_uv,
    const float* __restrict__ ln_gamma,
    const float* __restrict__ q_gamma,
    const float* __restrict__ k_gamma,
    const float* __restrict__ Wq,     // [192][384]
    const float* __restrict__ Wkv,    // [154][768]
    const float* __restrict__ Wout,   // [384][384]
    const int*   __restrict__ idx_ws,
    float* __restrict__ out)          // [B][HW][384]
{
  __shared__ float s_X[NJ][XST];        // one K-half of the 64 kv rows (20.7KB)
  __shared__ float s_regA[QT][INNER];   // q (raw->normed), later attn_out
  __shared__ float s_regB[48 * XST];    // ln rows (8x192 alias), later xbar[rhl][kk]
  __shared__ float s_scores[NJ][NH_];
  __shared__ float s_attn[QT][NH_][K_];
  __shared__ float s_mask[NJ];
  __shared__ int   s_idx[NJ];
  __shared__ float s_offx[NJ];
  __shared__ float s_offy[NJ];
  __shared__ float s_norm[QT * NH_];

  const int tid = threadIdx.x;
  const int b   = blockIdx.y;
  const int q0  = blockIdx.x * QT;

  // K-GEMM thread geometry (used across phases S4..S6)
  const int tc  = tid & 15;          // col-chunk within head: cols tc*4..tc*4+3
  const int tj  = tid >> 4;          // row group: rows 4tj..4tj+3
  const int tc4 = tc * 4;
  const int j0  = tj * 4;
  const int r4  = tj >> 1;           // query row shared by rows j0..j0+3

  // ---- S1: gather idx/offsets/mask (64 thr) + LayerNorm (all) -------------
  if (tid < NJ) {
    const int j  = tid;
    const int q  = q0 + (j >> 3);
    const int id = idx_ws[((size_t)b * HW_ + q) * K_ + (j & 7)];
    s_idx[j] = id;
    const float ax = img_uv[id * 2], ay = img_uv[id * 2 + 1];
    const float bx = img_uv[q * 2],  by = img_uv[q * 2 + 1];
    s_offx[j] = ax - bx; s_offy[j] = ay - by;
    const double dox = (double)ax - (double)bx;
    const double doy = (double)ay - (double)by;
    s_mask[j] = (dox * dox + doy * doy <= 0.010000000000000002) ? 1.f : 0.f;
  }
  {
    const int r  = ((tid >> 6) << 1) | ((tid >> 5) & 1);
    const int sl = tid & 31;
    const float* row = feat_2d + ((size_t)b * HW_ + q0 + r) * IMGD;
    float x[6]; float sum = 0.f, ssq = 0.f;
#pragma unroll
    for (int i = 0; i < 6; ++i) { x[i] = row[sl + 32 * i]; sum += x[i]; ssq += x[i] * x[i]; }
#pragma unroll
    for (int m = 16; m >= 1; m >>= 1) { sum += __shfl_xor(sum, m); ssq += __shfl_xor(ssq, m); }
    const float mu = sum * (1.f / 192.f);
    float var = ssq * (1.f / 192.f) - mu * mu;
    var = fmaxf(var, 0.f);
    const float rstd = rsqrtf(var + 1e-5f);
    float* lnr = s_regB + r * IMGD;
#pragma unroll
    for (int i = 0; i < 6; ++i) {
      const int c = sl + 32 * i;
      lnr[c] = (x[i] - mu) * rstd * ln_gamma[c];
    }
  }
  __syncthreads();

  // ---- S2: Q projection (raw q -> s_regA) + stage X half0 -----------------
  {
    const int r  = tid >> 5;
    const int c0 = (tid & 31) * 12;
    const float* lnr = s_regB + r * IMGD;
    float acc[12];
#pragma unroll
    for (int i = 0; i < 12; ++i) acc[i] = 0.f;
#pragma unroll 2
    for (int kk = 0; kk < IMGD; ++kk) {
      const float xv = lnr[kk];
      const float4* wp = reinterpret_cast<const float4*>(Wq + (size_t)kk * INNER + c0);
      const float4 w0 = wp[0], w1 = wp[1], w2 = wp[2];
      acc[0] += xv * w0.x; acc[1] += xv * w0.y; acc[2]  += xv * w0.z; acc[3]  += xv * w0.w;
      acc[4] += xv * w1.x; acc[5] += xv * w1.y; acc[6]  += xv * w1.z; acc[7]  += xv * w1.w;
      acc[8] += xv * w2.x; acc[9] += xv * w2.y; acc[10] += xv * w2.z; acc[11] += xv * w2.w;
    }
#pragma unroll
    for (int i = 0; i < 12; ++i) s_regA[r][c0 + i] = acc[i];
  }
  {
    // stage X half0: f3 cols 0..79 (5 float4 per thread)
    const int j = tid >> 2, tsub = tid & 3;
    const int id = s_idx[j];
    const float4* f4 = reinterpret_cast<const float4*>(feat_3d + ((size_t)b * HW_ + id) * PTD) + tsub * 5;
    float* xr = s_X[j];
#pragma unroll
    for (int i = 0; i < 5; ++i) {
      const float4 v = f4[i];
      const int c = tsub * 20 + i * 4;
      xr[c] = v.x; xr[c + 1] = v.y; xr[c + 2] = v.z; xr[c + 3] = v.w;
    }
  }
  __syncthreads();

  // ---- S3: q norms (48 thr) ----------------------------------------------
  if (tid < QT * NH_) {
    const int r = tid / NH_, h = tid % NH_;
    const float* v = &s_regA[r][h * DH_];
    float ss = 0.f;
#pragma unroll
    for (int d = 0; d < DH_; ++d) ss += v[d] * v[d];
    s_norm[tid] = fmaxf(sqrtf(ss), 1e-12f);
  }
  __syncthreads();

  // K accumulators live S4..S6
  float acc[NH_][4][4];
#pragma unroll
  for (int h = 0; h < NH_; ++h)
#pragma unroll
    for (int a = 0; a < 4; ++a)
#pragma unroll
      for (int i = 0; i < 4; ++i) acc[h][a][i] = 0.f;

  auto kgemm = [&](int ncols, int wrow0) {
    for (int kk = 0; kk < ncols; ++kk) {
      const float* wr = Wkv + (size_t)(wrow0 + kk) * (2 * INNER);
      float4 w[NH_];
#pragma unroll
      for (int h = 0; h < NH_; ++h)
        w[h] = *reinterpret_cast<const float4*>(wr + h * DH_ + tc4);
      float xv[4];
#pragma unroll
      for (int a = 0; a < 4; ++a) xv[a] = s_X[j0 + a][kk];
#pragma unroll
      for (int h = 0; h < NH_; ++h)
#pragma unroll
        for (int a = 0; a < 4; ++a) {
          acc[h][a][0] += xv[a] * w[h].x; acc[h][a][1] += xv[a] * w[h].y;
          acc[h][a][2] += xv[a] * w[h].z; acc[h][a][3] += xv[a] * w[h].w;
        }
    }
  };

  // ---- S4: scale q in place (norm + gamma) , K-GEMM half0 -----------------
  {
    const int r  = tid >> 5;
    const int c0 = (tid & 31) * 12;
#pragma unroll
    for (int i = 0; i < 12; ++i) {
      const int c = c0 + i;
      const float n = s_norm[r * NH_ + (c >> 6)];
      s_regA[r][c] *= (8.f / n) * q_gamma[c];
    }
  }
  kgemm(HK0, 0);
  __syncthreads();

  // ---- S5: stage X half1 (f3 cols 80..127 + 26 pos dims) ------------------
  {
    const int j = tid >> 2, tsub = tid & 3;
    const int id = s_idx[j];
    const float4* f4 = reinterpret_cast<const float4*>(feat_3d + ((size_t)b * HW_ + id) * PTD) + 20 + tsub * 3;
    float* xr = s_X[j];
#pragma unroll
    for (int i = 0; i < 3; ++i) {
      const float4 v = f4[i];
      const int c = tsub * 12 + i * 4;       // local cols 0..47 = f3 80..127
      xr[c] = v.x; xr[c + 1] = v.y; xr[c + 2] = v.z; xr[c + 3] = v.w;
    }
    if (tsub == 0) {
      const float ox = s_offx[j], oy = s_offy[j];
#pragma unroll
      for (int m = 0; m < 6; ++m) {
        const float fr = (float)(1 << m);
        float sx, cx, sy, cy;
        sincosf(ox * fr, &sx, &cx);
        sincosf(oy * fr, &sy, &cy);
        xr[48 + m] = sx; xr[54 + m] = sy;    // sin(ox f), sin(oy f)  (g128..139)
        xr[60 + m] = cx; xr[66 + m] = cy;    // cos(ox f), cos(oy f)  (g140..151)
      }
      xr[72] = ox; xr[73] = oy;              // g152, g153
    }
  }
  __syncthreads();

  // ---- S6: K-GEMM half1 + k-RMSNorm + scores ------------------------------
  kgemm(HK1, HK0);
  {
#pragma unroll
    for (int h = 0; h < NH_; ++h) {
      const int cb = h * DH_ + tc4;
      const float g0 = k_gamma[cb + 0], g1 = k_gamma[cb + 1];
      const float g2 = k_gamma[cb + 2], g3 = k_gamma[cb + 3];
      const float q0v = s_regA[r4][cb + 0], q1v = s_regA[r4][cb + 1];
      const float q2v = s_regA[r4][cb + 2], q3v = s_regA[r4][cb + 3];
      float ss[4], sc[4];
#pragma unroll
      for (int a = 0; a < 4; ++a) {
        ss[a] = acc[h][a][0] * acc[h][a][0] + acc[h][a][1] * acc[h][a][1]
              + acc[h][a][2] * acc[h][a][2] + acc[h][a][3] * acc[h][a][3];
        sc[a] = acc[h][a][0] * q0v * g0 + acc[h][a][1] * q1v * g1
              + acc[h][a][2] * q2v * g2 + acc[h][a][3] * q3v * g3;
      }
#pragma unroll
      for (int m = 1; m < 16; m <<= 1) {
#pragma unroll
        for (int a = 0; a < 4; ++a) {
          ss[a] += __shfl_xor(ss[a], m);
          sc[a] += __shfl_xor(sc[a], m);
        }
      }
      if (tc == 0) {
#pragma unroll
        for (int a = 0; a < 4; ++a) {
          const float n = fmaxf(sqrtf(ss[a]), 1e-12f);
          s_scores[j0 + a][h] = (8.f / n) * sc[a];
        }
      }
    }
  }
  __syncthreads();

  // ---- S7: masked softmax (48 thr) ----------------------------------------
  if (tid < QT * NH_) {
    const int r = tid / NH_, h = tid % NH_;
    float s[K_]; float mx = -1e38f;
#pragma unroll
    for (int k = 0; k < K_; ++k) {
      float v = s_scores[r * K_ + k][h];
      if (s_mask[r * K_ + k] == 0.f) v = -1e30f;
      s[k] = v; mx = fmaxf(mx, v);
    }
    float sum = 0.f;
#pragma unroll
    for (int k = 0; k < K_; ++k) { const float pp = expf(s[k] - mx); s[k] = pp; sum += pp; }
    const float inv = 1.f / sum;
#pragma unroll
    for (int k = 0; k < K_; ++k) s_attn[r][h][k] = s[k] * inv;
  }
  __syncthreads();

  auto xbar = [&](int ncols) {
    const int tot = 48 * ncols;
    for (int o = tid; o < tot; o += 256) {
      const int rhl = o / ncols, kk = o - rhl * ncols;
      const int rr = rhl / 6, hh = rhl - rr * 6;
      const float* at = s_attn[rr][hh];
      const float* xc = &s_X[rr * 8][kk];
      float a = 0.f;
#pragma unroll
      for (int k = 0; k < K_; ++k) a += at[k] * xc[k * XST];
      s_regB[rhl * XST + kk] = a;
    }
  };

  auto vgemm = [&](int ncols, int wrow0, bool first) {
    float a0[6], a1[6];
    const float* xb[6]; const float* wv[6];
    int rr[6], hh[6], dd[6];
#pragma unroll
    for (int i = 0; i < 6; ++i) {
      const int o = tid + 256 * i;           // 0..1535
      const int rh = o >> 5;
      dd[i] = (o & 31) * 2;
      rr[i] = rh / 6; hh[i] = rh - rr[i] * 6;
      xb[i] = s_regB + rh * XST;
      wv[i] = Wkv + (size_t)wrow0 * (2 * INNER) + INNER + hh[i] * DH_ + dd[i];
      a0[i] = 0.f; a1[i] = 0.f;
    }
    for (int kk = 0; kk < ncols; ++kk) {
#pragma unroll
      for (int i = 0; i < 6; ++i) {
        const float xv = xb[i][kk];
        const float2 w = *reinterpret_cast<const float2*>(wv[i] + (size_t)kk * (2 * INNER));
        a0[i] += xv * w.x; a1[i] += xv * w.y;
      }
    }
#pragma unroll
    for (int i = 0; i < 6; ++i) {
      float* dst = &s_regA[rr[i]][hh[i] * DH_ + dd[i]];
      if (first) { dst[0] = a0[i]; dst[1] = a1[i]; }
      else       { dst[0] += a0[i]; dst[1] += a1[i]; }
    }
  };

  // ---- S8: xbar for resident half1 ----------------------------------------
  xbar(HK1);
  __syncthreads();

  // ---- S9: V-GEMM half1 (init attn_out in s_regA) + restage X half0 -------
  {
    // issue global loads for half0 restage early (hide under V-GEMM)
    const int j = tid >> 2, tsub = tid & 3;
    const int id = s_idx[j];
    const float4* f4 = reinterpret_cast<const float4*>(feat_3d + ((size_t)b * HW_ + id) * PTD) + tsub * 5;
    float4 st[5];
#pragma unroll
    for (int i = 0; i < 5; ++i) st[i] = f4[i];

    vgemm(HK1, HK0, true);

    float* xr = s_X[j];
#pragma unroll
    for (int i = 0; i < 5; ++i) {
      const int c = tsub * 20 + i * 4;
      xr[c] = st[i].x; xr[c + 1] = st[i].y; xr[c + 2] = st[i].z; xr[c + 3] = st[i].w;
    }
  }
  __syncthreads();

  // ---- S10: xbar for half0 ------------------------------------------------
  xbar(HK0);
  __syncthreads();

  // ---- S11: V-GEMM half0 (accumulate) -------------------------------------
  vgemm(HK0, 0, false);
  __syncthreads();

  // ---- S12: output projection ---------------------------------------------
  {
    const int r  = tid >> 5;
    const int c0 = (tid & 31) * 12;
    float oacc[12];
#pragma unroll
    for (int i = 0; i < 12; ++i) oacc[i] = 0.f;
#pragma unroll 2
    for (int cc = 0; cc < INNER; ++cc) {
      const float av = s_regA[r][cc];
      const float4* wp = reinterpret_cast<const float4*>(Wout + (size_t)cc * INNER + c0);
      const float4 w0 = wp[0], w1 = wp[1], w2 = wp[2];
      oacc[0] += av * w0.x; oacc[1] += av * w0.y; oacc[2]  += av * w0.z; oacc[3]  += av * w0.w;
      oacc[4] += av * w1.x; oacc[5] += av * w1.y; oacc[6]  += av * w1.z; oacc[7]  += av * w1.w;
      oacc[8] += av * w2.x; oacc[9] += av * w2.y; oacc[10] += av * w2.z; oacc[11] += av * w2.w;
    }
    float* orow = out + ((size_t)b * HW_ + q0 + r) * INNER + c0;
#pragma unroll
    for (int i = 0; i < 12; ++i) orow[i] = oacc[i];
  }
}

// ---------------------------------------------------------------------------
extern "C" void kernel_launch(void* const* d_in, const int* in_sizes, int n_in,
                              void* d_out, int out_size, void* d_ws, size_t ws_size,
                              hipStream_t stream) {
  (void)in_sizes; (void)n_in; (void)out_size; (void)ws_size;
  const float* feat_2d = (const float*)d_in[0];
  const float* feat_3d = (const float*)d_in[1];
  const float* proj_uv = (const float*)d_in[2];
  const float* img_uv  = (const float*)d_in[3];
  const float* ln_g    = (const float*)d_in[4];
  const float* q_g     = (const float*)d_in[5];
  const float* k_g     = (const float*)d_in[6];
  const float* Wq      = (const float*)d_in[7];
  const float* Wkv     = (const float*)d_in[8];
  const float* Wout    = (const float*)d_in[9];
  float* out   = (float*)d_out;
  int*  idx_ws = (int*)d_ws;   // B*HW*K int32 = 614,400 B

  knn_kernel<<<dim3(B_ * HW_ / 4), 256, 0, stream>>>(proj_uv, img_uv, idx_ws);
  fused_kernel<<<dim3(HW_ / QT, B_), 256, 0, stream>>>(
      feat_2d, feat_3d, img_uv, ln_g, q_g, k_g, Wq, Wkv, Wout, idx_ws, out);
}

// Round 5
// 905.940 us; speedup vs baseline: 1.5316x; 1.5316x over previous
//
#include <hip/hip_runtime.h>
#include <math.h>

#define B_    4
#define HW_   4800
#define K_    8
#define IMGD  192
#define PTD   128
#define NH_   6
#define DH_   64
#define INNER 384
#define KVIN  154     // PTD + 26 pos dims
#define QT    8       // queries per block
#define NJ    64      // QT * K_
#define XLD   155     // fp32 xbar stride in s_regB
#define XBS   168     // bf16 X row stride (21*16B -> 2-way banks, 16B aligned)
#define AST   392     // bf16 attn_out row stride
#define KT_K  5       // K-GEMM k-steps (154 -> 160)
#define KT_O  12      // out-proj k-steps (384)

typedef __attribute__((ext_vector_type(8))) short bf16x8;
typedef __attribute__((ext_vector_type(4))) float f32x4;

__device__ __forceinline__ unsigned short f2bf(float x) {
  unsigned u = __float_as_uint(x);
  return (unsigned short)((u + 0x7FFFu + ((u >> 16) & 1u)) >> 16);  // RNE
}
__device__ __forceinline__ float bf2f(unsigned short s) {
  return __uint_as_float(((unsigned)s) << 16);
}

// ---------------------------------------------------------------------------
// Kernel 0: pack weights into MFMA fragment order (lane l, reg j):
//   k = kt*32 + (l>>4)*8 + j,  n = nt*16 + (l&15)
// Wk (cols 0..383 of Wkv) as hi/lo split-bf16; Wout as plain bf16.
// ---------------------------------------------------------------------------
__global__ __launch_bounds__(256) void pack_kernel(
    const float* __restrict__ Wkv, const float* __restrict__ Wout,
    unsigned short* __restrict__ pkh, unsigned short* __restrict__ pkl,
    unsigned short* __restrict__ pwo)
{
  const int o = blockIdx.x * 256 + threadIdx.x;
  const int NK = 24 * KT_K * 64 * 8;          // 61440
  if (o < NK) {
    const int j = o & 7, l = (o >> 3) & 63, rest = o >> 9;
    const int kt = rest % KT_K, nt = rest / KT_K;
    const int k = kt * 32 + ((l >> 4) << 3) + j;
    const int n = nt * 16 + (l & 15);
    const float v = (k < KVIN) ? Wkv[(size_t)k * (2 * INNER) + n] : 0.f;
    const unsigned short h = f2bf(v);
    pkh[o] = h;
    pkl[o] = f2bf(v - bf2f(h));
  } else {
    const int o2 = o - NK;
    if (o2 < 24 * KT_O * 64 * 8) {            // 147456
      const int j = o2 & 7, l = (o2 >> 3) & 63, rest = o2 >> 9;
      const int kt = rest % KT_O, nt = rest / KT_O;
      const int k = kt * 32 + ((l >> 4) << 3) + j;
      const int n = nt * 16 + (l & 15);
      pwo[o2] = f2bf(Wout[(size_t)k * INNER + n]);
    }
  }
}

// ---------------------------------------------------------------------------
// Kernel 1: brute-force kNN (verified r3: BLAS-style f32 expanded distance).
// ---------------------------------------------------------------------------
__global__ __launch_bounds__(256) void knn_kernel(
    const float* __restrict__ proj_uv,
    const float* __restrict__ img_uv,
    int* __restrict__ idx_out)
{
#pragma clang fp contract(off)
  __shared__ float s_px[HW_];
  __shared__ float s_py[HW_];
  __shared__ float s_cd[256][K_];
  __shared__ int   s_ci[256][K_];

  const int tid  = threadIdx.x;
  const int wave = tid >> 6;
  const int lane = tid & 63;
  const int blk  = blockIdx.x;
  const int b    = blk / (HW_ / 4);
  const int q    = (blk % (HW_ / 4)) * 4 + wave;

  const float2* pv = reinterpret_cast<const float2*>(proj_uv + (size_t)b * HW_ * 2);
  for (int i = tid; i < HW_; i += 256) {
    float2 p = pv[i];
    s_px[i] = p.x; s_py[i] = p.y;
  }
  __syncthreads();

  const float qx = img_uv[q * 2 + 0];
  const float qy = img_uv[q * 2 + 1];
  const float sqq = qx * qx + qy * qy;

  float dist[K_];
  int   ind[K_];
#pragma unroll
  for (int s = 0; s < K_; ++s) { dist[s] = 3.4e38f; ind[s] = 0x7fffffff; }

  for (int n = lane; n < HW_; n += 64) {
    const float px = s_px[n], py = s_py[n];
    const float sqp = px * px + py * py;
    const float dot = fmaf(qy, py, qx * px);
    const float d   = (sqq + sqp) - 2.0f * dot;
    if (d < dist[K_ - 1]) {
      bool placed = false;
#pragma unroll
      for (int s = K_ - 1; s >= 1; --s) {
        if (!placed) {
          if (d < dist[s - 1]) { dist[s] = dist[s - 1]; ind[s] = ind[s - 1]; }
          else                 { dist[s] = d; ind[s] = n; placed = true; }
        }
      }
      if (!placed) { dist[0] = d; ind[0] = n; }
    }
  }

#pragma unroll
  for (int s = 0; s < K_; ++s) { s_cd[tid][s] = dist[s]; s_ci[tid][s] = ind[s]; }

  int p = 0;
#pragma unroll
  for (int r = 0; r < K_; ++r) {
    float hd = (p < K_) ? s_cd[tid][p] : 3.4e38f;
    int   hi = (p < K_) ? s_ci[tid][p] : 0x7fffffff;
    float bd = hd; int bi = hi;
#pragma unroll
    for (int m = 1; m < 64; m <<= 1) {
      float od = __shfl_xor(bd, m);
      int   oi = __shfl_xor(bi, m);
      if (od < bd || (od == bd && oi < bi)) { bd = od; bi = oi; }
    }
    if (hd == bd && hi == bi) p++;
    if (lane == r) idx_out[((size_t)b * HW_ + q) * K_ + r] = bi;
  }
}

// ---------------------------------------------------------------------------
// Kernel 2: fused pipeline. K-GEMM = split-bf16 MFMA (3 passes, exact to
// ~2^-17 so softmax is safe); out-proj = plain bf16 MFMA; Q-proj/V fp32.
// ---------------------------------------------------------------------------
__global__ __launch_bounds__(256) void fused_kernel(
    const float* __restrict__ feat_2d,
    const float* __restrict__ feat_3d,
    const float* __restrict__ img_uv,
    const float* __restrict__ ln_gamma,
    const float* __restrict__ q_gamma,
    const float* __restrict__ k_gamma,
    const float* __restrict__ Wq,
    const float* __restrict__ Wkv,
    const unsigned short* __restrict__ pkh,
    const unsigned short* __restrict__ pkl,
    const unsigned short* __restrict__ pwo,
    const int*   __restrict__ idx_ws,
    float* __restrict__ out)
{
  __shared__ unsigned short s_Xh[NJ][XBS];   // X hi (bf16), rows 0..63, k 0..159(+pad)
  __shared__ unsigned short s_Xl[NJ][XBS];   // X lo
  __shared__ float s_regA[QT][INNER];        // raw q -> qn -> attn_out
  __shared__ float s_regB[24 * XLD];         // LN rows (alias), later xbar chunk
  __shared__ float s_scores[NJ][NH_];
  __shared__ float s_attn[QT][NH_][K_];
  __shared__ float s_mask[NJ];
  __shared__ int   s_idx[NJ];
  __shared__ float s_offx[NJ];
  __shared__ float s_offy[NJ];
  __shared__ float s_norm[QT * NH_];

  const int tid = threadIdx.x;
  const int b   = blockIdx.y;
  const int q0  = blockIdx.x * QT;
  const int l   = tid & 63;
  const int w   = tid >> 6;
  const int lm  = l & 15;
  const int lg  = l >> 4;

  // ---- S1: gather idx/offsets/mask (64 thr) + LayerNorm (all) -------------
  if (tid < NJ) {
    const int j  = tid;
    const int q  = q0 + (j >> 3);
    const int id = idx_ws[((size_t)b * HW_ + q) * K_ + (j & 7)];
    s_idx[j] = id;
    const float ax = img_uv[id * 2], ay = img_uv[id * 2 + 1];
    const float bx = img_uv[q * 2],  by = img_uv[q * 2 + 1];
    s_offx[j] = ax - bx; s_offy[j] = ay - by;
    const double dox = (double)ax - (double)bx;
    const double doy = (double)ay - (double)by;
    s_mask[j] = (dox * dox + doy * doy <= 0.010000000000000002) ? 1.f : 0.f;
  }
  {
    const int r  = ((tid >> 6) << 1) | ((tid >> 5) & 1);
    const int sl = tid & 31;
    const float* row = feat_2d + ((size_t)b * HW_ + q0 + r) * IMGD;
    float x[6]; float sum = 0.f, ssq = 0.f;
#pragma unroll
    for (int i = 0; i < 6; ++i) { x[i] = row[sl + 32 * i]; sum += x[i]; ssq += x[i] * x[i]; }
#pragma unroll
    for (int m = 16; m >= 1; m >>= 1) { sum += __shfl_xor(sum, m); ssq += __shfl_xor(ssq, m); }
    const float mu = sum * (1.f / 192.f);
    float var = ssq * (1.f / 192.f) - mu * mu;
    var = fmaxf(var, 0.f);
    const float rstd = rsqrtf(var + 1e-5f);
    float* lnr = s_regB + r * IMGD;
#pragma unroll
    for (int i = 0; i < 6; ++i) {
      const int c = sl + 32 * i;
      lnr[c] = (x[i] - mu) * rstd * ln_gamma[c];
    }
  }
  __syncthreads();

  // ---- S2: Q projection (fp32) + X stage/convert to hi/lo bf16 ------------
  {
    const int r  = tid >> 5;
    const int c0 = (tid & 31) * 12;
    const float* lnr = s_regB + r * IMGD;
    float acc[12];
#pragma unroll
    for (int i = 0; i < 12; ++i) acc[i] = 0.f;
#pragma unroll 2
    for (int kk = 0; kk < IMGD; ++kk) {
      const float xv = lnr[kk];
      const float4* wp = reinterpret_cast<const float4*>(Wq + (size_t)kk * INNER + c0);
      const float4 w0 = wp[0], w1 = wp[1], w2 = wp[2];
      acc[0] += xv * w0.x; acc[1] += xv * w0.y; acc[2]  += xv * w0.z; acc[3]  += xv * w0.w;
      acc[4] += xv * w1.x; acc[5] += xv * w1.y; acc[6]  += xv * w1.z; acc[7]  += xv * w1.w;
      acc[8] += xv * w2.x; acc[9] += xv * w2.y; acc[10] += xv * w2.z; acc[11] += xv * w2.w;
    }
#pragma unroll
    for (int i = 0; i < 12; ++i) s_regA[r][c0 + i] = acc[i];
  }
  {
    const int j = tid >> 2, tsub = tid & 3;
    const int id = s_idx[j];
    const float4* f4 = reinterpret_cast<const float4*>(feat_3d + ((size_t)b * HW_ + id) * PTD) + tsub * 8;
    unsigned* dh = (unsigned*)&s_Xh[j][0];
    unsigned* dl = (unsigned*)&s_Xl[j][0];
#pragma unroll
    for (int i = 0; i < 8; ++i) {
      const float4 v = f4[i];
      const int u = (tsub * 32 + i * 4) >> 1;     // uint index
      const unsigned short h0 = f2bf(v.x), h1 = f2bf(v.y);
      const unsigned short h2 = f2bf(v.z), h3 = f2bf(v.w);
      dh[u]     = (unsigned)h0 | ((unsigned)h1 << 16);
      dh[u + 1] = (unsigned)h2 | ((unsigned)h3 << 16);
      const unsigned short l0 = f2bf(v.x - bf2f(h0)), l1 = f2bf(v.y - bf2f(h1));
      const unsigned short l2 = f2bf(v.z - bf2f(h2)), l3 = f2bf(v.w - bf2f(h3));
      dl[u]     = (unsigned)l0 | ((unsigned)l1 << 16);
      dl[u + 1] = (unsigned)l2 | ((unsigned)l3 << 16);
    }
    if (tsub == 0) {
      const float ox = s_offx[j], oy = s_offy[j];
      float pv[32];
#pragma unroll
      for (int m = 0; m < 6; ++m) {
        const float fr = (float)(1 << m);
        float sx, cx, sy, cy;
        sincosf(ox * fr, &sx, &cx);
        sincosf(oy * fr, &sy, &cy);
        pv[m] = sx; pv[6 + m] = sy; pv[12 + m] = cx; pv[18 + m] = cy;
      }
      pv[24] = ox; pv[25] = oy;
#pragma unroll
      for (int i = 26; i < 32; ++i) pv[i] = 0.f;   // zero-pad k=154..159
      unsigned* ph = (unsigned*)&s_Xh[j][128];
      unsigned* pl = (unsigned*)&s_Xl[j][128];
#pragma unroll
      for (int p = 0; p < 16; ++p) {
        const float a = pv[2 * p], c = pv[2 * p + 1];
        const unsigned short ah = f2bf(a), ch = f2bf(c);
        ph[p] = (unsigned)ah | ((unsigned)ch << 16);
        const unsigned short al = f2bf(a - bf2f(ah)), cl = f2bf(c - bf2f(ch));
        pl[p] = (unsigned)al | ((unsigned)cl << 16);
      }
    }
  }
  __syncthreads();

  // ---- S3: q norms (48 thr) -----------------------------------------------
  if (tid < QT * NH_) {
    const int r = tid / NH_, h = tid % NH_;
    const float* v = &s_regA[r][h * DH_];
    float ss = 0.f;
#pragma unroll
    for (int d = 0; d < DH_; ++d) ss += v[d] * v[d];
    s_norm[tid] = fmaxf(sqrtf(ss), 1e-12f);
  }
  __syncthreads();

  // ---- S4: scale q in place -----------------------------------------------
  {
    const int r  = tid >> 5;
    const int c0 = (tid & 31) * 12;
#pragma unroll
    for (int i = 0; i < 12; ++i) {
      const int c = c0 + i;
      const float n = s_norm[r * NH_ + (c >> 6)];
      s_regA[r][c] *= (8.f / n) * q_gamma[c];
    }
  }
  __syncthreads();

  // ---- S5: K-GEMM via split-bf16 MFMA + fused k-RMSNorm + scores ----------
  // wave w owns kv rows 16w..16w+15 (queries 2w, 2w+1).
  {
    const int m0 = 16 * w;
    const unsigned short* xh = &s_Xh[m0 + lm][lg << 3];
    const unsigned short* xl = &s_Xl[m0 + lm][lg << 3];
    const int rq = 2 * w + (lg >> 1);         // query row for this lane's acc rows
    for (int h = 0; h < NH_; ++h) {
      f32x4 acc[4];
#pragma unroll
      for (int t = 0; t < 4; ++t) acc[t] = (f32x4){0.f, 0.f, 0.f, 0.f};
#pragma unroll
      for (int kt = 0; kt < KT_K; ++kt) {
        const bf16x8 ah = *(const bf16x8*)(xh + kt * 32);
        const bf16x8 al = *(const bf16x8*)(xl + kt * 32);
#pragma unroll
        for (int t = 0; t < 4; ++t) {
          const int nt = h * 4 + t;
          const size_t bo = ((size_t)(nt * KT_K + kt) * 64 + l) * 8;
          const bf16x8 bh = *(const bf16x8*)(pkh + bo);
          const bf16x8 bl = *(const bf16x8*)(pkl + bo);
          acc[t] = __builtin_amdgcn_mfma_f32_16x16x32_bf16(ah, bh, acc[t], 0, 0, 0);
          acc[t] = __builtin_amdgcn_mfma_f32_16x16x32_bf16(al, bh, acc[t], 0, 0, 0);
          acc[t] = __builtin_amdgcn_mfma_f32_16x16x32_bf16(ah, bl, acc[t], 0, 0, 0);
        }
      }
      // C-layout (m89): row = m0 + lg*4 + reg, col = nt*16 + lm
      float ss[4], sc[4];
#pragma unroll
      for (int reg = 0; reg < 4; ++reg) { ss[reg] = 0.f; sc[reg] = 0.f; }
#pragma unroll
      for (int t = 0; t < 4; ++t) {
        const int n = h * DH_ + t * 16 + lm;
        const float qg = s_regA[rq][n] * k_gamma[n];
#pragma unroll
        for (int reg = 0; reg < 4; ++reg) {
          const float v = acc[t][reg];
          ss[reg] += v * v;
          sc[reg] += v * qg;
        }
      }
#pragma unroll
      for (int m = 1; m < 16; m <<= 1) {
#pragma unroll
        for (int reg = 0; reg < 4; ++reg) {
          ss[reg] += __shfl_xor(ss[reg], m);
          sc[reg] += __shfl_xor(sc[reg], m);
        }
      }
      if (lm == 0) {
#pragma unroll
        for (int reg = 0; reg < 4; ++reg) {
          const float nn = fmaxf(sqrtf(ss[reg]), 1e-12f);
          s_scores[m0 + (lg << 2) + reg][h] = (8.f / nn) * sc[reg];
        }
      }
    }
  }
  __syncthreads();

  // ---- S6: masked softmax (48 thr) ----------------------------------------
  if (tid < QT * NH_) {
    const int r = tid / NH_, h = tid % NH_;
    float s[K_]; float mx = -1e38f;
#pragma unroll
    for (int k = 0; k < K_; ++k) {
      float v = s_scores[r * K_ + k][h];
      if (s_mask[r * K_ + k] == 0.f) v = -1e30f;
      s[k] = v; mx = fmaxf(mx, v);
    }
    float sum = 0.f;
#pragma unroll
    for (int k = 0; k < K_; ++k) { const float pp = expf(s[k] - mx); s[k] = pp; sum += pp; }
    const float inv = 1.f / sum;
#pragma unroll
    for (int k = 0; k < K_; ++k) s_attn[r][h][k] = s[k] * inv;
  }
  __syncthreads();

  // ---- S7: xbar (fp32, X = hi+lo) + V-GEMM (fp32), 2 chunks of 3 heads ----
  for (int ch = 0; ch < 2; ++ch) {
    for (int o = tid; o < 24 * KVIN; o += 256) {
      const int rhl = o / KVIN, kk = o - rhl * KVIN;
      const int rr = rhl / 3, hh = ch * 3 + rhl % 3;
      const float* at = s_attn[rr][hh];
      float a = 0.f;
#pragma unroll
      for (int k = 0; k < K_; ++k) {
        const int row = rr * 8 + k;
        const float xv = bf2f(s_Xh[row][kk]) + bf2f(s_Xl[row][kk]);
        a += at[k] * xv;
      }
      s_regB[rhl * XLD + kk] = a;
    }
    __syncthreads();
    for (int o = tid; o < 24 * DH_; o += 256) {
      const int rhl = o >> 6, d = o & 63;
      const int rr = rhl / 3, hh = ch * 3 + rhl % 3;
      const float* xb = s_regB + rhl * XLD;
      const float* wv = Wkv + (size_t)INNER + hh * DH_ + d;
      float a = 0.f;
      for (int kk = 0; kk < KVIN; ++kk) a += xb[kk] * wv[(size_t)kk * (2 * INNER)];
      s_regA[rr][hh * DH_ + d] = a;
    }
    __syncthreads();
  }

  // ---- S8: convert attn_out -> bf16 [16][AST] (carved from s_Xh), pad 0 ---
  unsigned short* aout = &s_Xh[0][0];   // 16*392 = 6272 shorts <= 64*168
  {
    unsigned* ao = (unsigned*)aout;
    for (int o = tid; o < 16 * (AST / 2); o += 256) {
      const int row = o / (AST / 2);
      const int c   = (o - row * (AST / 2)) * 2;
      unsigned val = 0u;
      if (row < 8 && c < INNER) {
        const unsigned short h0 = f2bf(s_regA[row][c]);
        const unsigned short h1 = f2bf(s_regA[row][c + 1]);
        val = (unsigned)h0 | ((unsigned)h1 << 16);
      }
      ao[o] = val;
    }
  }
  __syncthreads();

  // ---- S9: out-projection via plain bf16 MFMA; wave w -> n-tiles 6w..6w+5 -
  {
    f32x4 acc[6];
#pragma unroll
    for (int t = 0; t < 6; ++t) acc[t] = (f32x4){0.f, 0.f, 0.f, 0.f};
    const unsigned short* ar = aout + lm * AST + (lg << 3);
#pragma unroll 2
    for (int kt = 0; kt < KT_O; ++kt) {
      const bf16x8 a = *(const bf16x8*)(ar + kt * 32);
#pragma unroll
      for (int t = 0; t < 6; ++t) {
        const int nt = w * 6 + t;
        const bf16x8 bfr = *(const bf16x8*)(pwo + ((size_t)(nt * KT_O + kt) * 64 + l) * 8);
        acc[t] = __builtin_amdgcn_mfma_f32_16x16x32_bf16(a, bfr, acc[t], 0, 0, 0);
      }
    }
    if (lg < 2) {
      float* orow0 = out + ((size_t)b * HW_ + q0) * INNER;
#pragma unroll
      for (int reg = 0; reg < 4; ++reg) {
        const int m = (lg << 2) + reg;        // query row 0..7
#pragma unroll
        for (int t = 0; t < 6; ++t) {
          orow0[(size_t)m * INNER + (w * 6 + t) * 16 + lm] = acc[t][reg];
        }
      }
    }
  }
}

// ---------------------------------------------------------------------------
extern "C" void kernel_launch(void* const* d_in, const int* in_sizes, int n_in,
                              void* d_out, int out_size, void* d_ws, size_t ws_size,
                              hipStream_t stream) {
  (void)in_sizes; (void)n_in; (void)out_size; (void)ws_size;
  const float* feat_2d = (const float*)d_in[0];
  const float* feat_3d = (const float*)d_in[1];
  const float* proj_uv = (const float*)d_in[2];
  const float* img_uv  = (const float*)d_in[3];
  const float* ln_g    = (const float*)d_in[4];
  const float* q_g     = (const float*)d_in[5];
  const float* k_g     = (const float*)d_in[6];
  const float* Wq      = (const float*)d_in[7];
  const float* Wkv     = (const float*)d_in[8];
  const float* Wout    = (const float*)d_in[9];
  float* out   = (float*)d_out;

  // ws layout: idx (614400 B) | pkh (122880) | pkl (122880) | pwo (294912)
  int* idx_ws = (int*)d_ws;
  unsigned short* pkh = (unsigned short*)((char*)d_ws + 614400);
  unsigned short* pkl = pkh + 24 * KT_K * 64 * 8;
  unsigned short* pwo = pkl + 24 * KT_K * 64 * 8;

  pack_kernel<<<dim3(816), 256, 0, stream>>>(Wkv, Wout, pkh, pkl, pwo);
  knn_kernel<<<dim3(B_ * HW_ / 4), 256, 0, stream>>>(proj_uv, img_uv, idx_ws);
  fused_kernel<<<dim3(HW_ / QT, B_), 256, 0, stream>>>(
      feat_2d, feat_3d, img_uv, ln_g, q_g, k_g, Wq, Wkv,
      pkh, pkl, pwo, idx_ws, out);
}

// Round 7
// 320.386 us; speedup vs baseline: 4.3309x; 2.8277x over previous
//
#include <hip/hip_runtime.h>
#include <math.h>

#define B_    4
#define HW_   4800
#define K_    8
#define IMGD  192
#define PTD   128
#define NH_   6
#define DH_   64
#define INNER 384
#define KVIN  154
#define QT    8
#define NJ    64
#define XBS   168    // fp16 X row stride (336B = 21*16B, bank-spread)
#define AST   392    // fp16 alias row stride over s_regA (784B = 49*16B)
#define KTQ   6      // Q-proj k-steps (192)
#define KTK   5      // K/V k-steps (154 -> 160, zero-padded both sides)
#define KTO   12     // out-proj k-steps (384)

typedef _Float16 f16;
typedef __attribute__((ext_vector_type(8))) _Float16 f16x8;
typedef __attribute__((ext_vector_type(4))) float f32x4;

// ---------------------------------------------------------------------------
// Kernel 0: pack all weights into fp16 MFMA fragment order.
// frag(f) element (l, j):  k = kt*32 + (l>>4)*8 + j,  n = nt*16 + (l&15)
// layout: [pwq f=0..143 | pwk f=144..263 | pwv f=264..383 | pwo f=384..671]
// ---------------------------------------------------------------------------
__global__ __launch_bounds__(256) void pack_kernel(
    const float* __restrict__ Wq, const float* __restrict__ Wkv,
    const float* __restrict__ Wout, f16* __restrict__ pw)
{
  const int e = blockIdx.x * 256 + threadIdx.x;     // 672*512 = 344064 total
  if (e >= 672 * 512) return;
  const int f = e >> 9, r = e & 511, l = r >> 3, j = r & 7;
  const int lm = l & 15, kin = (l >> 4) * 8 + j;
  float v;
  if (f < 144) {                                    // Wq [192][384]
    const int nt = f / 6, kt = f % 6;
    v = Wq[(size_t)(kt * 32 + kin) * INNER + nt * 16 + lm];
  } else if (f < 264) {                             // Wk = Wkv[:, :384]
    const int g = f - 144, nt = g / 5, kt = g % 5, k = kt * 32 + kin;
    v = (k < KVIN) ? Wkv[(size_t)k * (2 * INNER) + nt * 16 + lm] : 0.f;
  } else if (f < 384) {                             // Wv = Wkv[:, 384:]
    const int g = f - 264, nt = g / 5, kt = g % 5, k = kt * 32 + kin;
    v = (k < KVIN) ? Wkv[(size_t)k * (2 * INNER) + INNER + nt * 16 + lm] : 0.f;
  } else {                                          // Wout [384][384]
    const int g = f - 384, nt = g / 12, kt = g % 12;
    v = Wout[(size_t)(kt * 32 + kin) * INNER + nt * 16 + lm];
  }
  pw[e] = (f16)v;
}

// ---------------------------------------------------------------------------
// Kernel 1: brute-force kNN. 2 queries per wave (2 independent insert chains
// hide the serial top-8 dependence). Distance = verified r3 BLAS-f32 form.
// ---------------------------------------------------------------------------
#define KNN_INIT(d, ind)                                                      \
  _Pragma("unroll") for (int s = 0; s < K_; ++s) { d[s] = 3.4e38f; ind[s] = 0x7fffffff; }

#define KNN_INSERT(dd, n, dist, ind)                                          \
  if (dd < dist[K_ - 1]) {                                                    \
    bool placed = false;                                                      \
    _Pragma("unroll") for (int s = K_ - 1; s >= 1; --s) {                     \
      if (!placed) {                                                          \
        if (dd < dist[s - 1]) { dist[s] = dist[s - 1]; ind[s] = ind[s - 1]; } \
        else                  { dist[s] = dd; ind[s] = n; placed = true; }    \
      }                                                                       \
    }                                                                         \
    if (!placed) { dist[0] = dd; ind[0] = n; }                                \
  }

#define KNN_MERGE(dist, ind, qidx)                                            \
  _Pragma("unroll") for (int r = 0; r < K_; ++r) {                            \
    float hd = dist[0]; int hi = ind[0];                                      \
    float bd = hd; int bi = hi;                                               \
    _Pragma("unroll") for (int m = 1; m < 64; m <<= 1) {                      \
      float od = __shfl_xor(bd, m); int oi = __shfl_xor(bi, m);               \
      if (od < bd || (od == bd && oi < bi)) { bd = od; bi = oi; }             \
    }                                                                         \
    const bool won = (hd == bd && hi == bi);                                  \
    _Pragma("unroll") for (int s = 0; s < K_ - 1; ++s) {                      \
      dist[s] = won ? dist[s + 1] : dist[s];                                  \
      ind[s]  = won ? ind[s + 1]  : ind[s];                                   \
    }                                                                         \
    dist[K_ - 1] = won ? 3.4e38f : dist[K_ - 1];                              \
    ind[K_ - 1]  = won ? 0x7fffffff : ind[K_ - 1];                            \
    if (lane == r) idx_out[((size_t)b * HW_ + (qidx)) * K_ + r] = bi;         \
  }

__global__ __launch_bounds__(256) void knn_kernel(
    const float* __restrict__ proj_uv,
    const float* __restrict__ img_uv,
    int* __restrict__ idx_out)
{
#pragma clang fp contract(off)
  __shared__ float2 s_p[HW_];                      // 38.4KB -> 4 blocks/CU

  const int tid  = threadIdx.x;
  const int wave = tid >> 6;
  const int lane = tid & 63;
  const int blk  = blockIdx.x;                     // 0..2399
  const int b    = blk / (HW_ / 8);
  const int qA   = (blk % (HW_ / 8)) * 8 + wave * 2;
  const int qB   = qA + 1;

  const float2* pv = reinterpret_cast<const float2*>(proj_uv + (size_t)b * HW_ * 2);
  for (int i = tid; i < HW_; i += 256) s_p[i] = pv[i];
  __syncthreads();

  const float qxA = img_uv[qA * 2], qyA = img_uv[qA * 2 + 1];
  const float qxB = img_uv[qB * 2], qyB = img_uv[qB * 2 + 1];
  const float sqqA = qxA * qxA + qyA * qyA;
  const float sqqB = qxB * qxB + qyB * qyB;

  float dA[K_], dB[K_];
  int   iA[K_], iB[K_];
  KNN_INIT(dA, iA);
  KNN_INIT(dB, iB);

  for (int n = lane; n < HW_; n += 64) {
    const float2 p = s_p[n];
    const float sqp = p.x * p.x + p.y * p.y;          // f32 no fma (pragma)
    const float dotA = fmaf(qyA, p.y, qxA * p.x);     // BLAS K=2 fma
    const float ddA  = (sqqA + sqp) - 2.0f * dotA;
    KNN_INSERT(ddA, n, dA, iA);
    const float dotB = fmaf(qyB, p.y, qxB * p.x);
    const float ddB  = (sqqB + sqp) - 2.0f * dotB;
    KNN_INSERT(ddB, n, dB, iB);
  }

  KNN_MERGE(dA, iA, qA);
  KNN_MERGE(dB, iB, qB);
}

// ---------------------------------------------------------------------------
// Kernel 2: fused pipeline — all four GEMMs via fp16 MFMA; waves partition
// n-tiles (each packed fragment read once per block). 38.4KB LDS -> 4 blk/CU.
// NaN-hygiene rule: every LDS byte an MFMA reads must be written first
// (uninit LDS can hold fp16 NaN patterns; NaN*0 = NaN — r6 failure mode).
// ---------------------------------------------------------------------------
__global__ __launch_bounds__(256, 4) void fused_kernel(
    const float* __restrict__ feat_2d,
    const float* __restrict__ feat_3d,
    const float* __restrict__ img_uv,
    const float* __restrict__ ln_gamma,
    const float* __restrict__ q_gamma,
    const float* __restrict__ k_gamma,
    const f16*   __restrict__ pw,
    const int*   __restrict__ idx_ws,
    float* __restrict__ out)
{
  __shared__ alignas(16) f16   s_X[NJ][XBS];       // 64 kv rows fp16 (21.5KB)
  __shared__ alignas(16) float s_regA[QT * AST];   // q fp32 | alias f16[16][392]
  __shared__ float s_scores[NJ][NH_];
  __shared__ float s_attn[QT][NH_][K_];
  __shared__ float s_mask[NJ];
  __shared__ int   s_idx[NJ];
  __shared__ float s_offx[NJ];
  __shared__ float s_offy[NJ];
  __shared__ float s_norm[QT * NH_];

  f16* s_f16 = reinterpret_cast<f16*>(s_regA);     // [16][AST]

  const int tid = threadIdx.x;
  const int b   = blockIdx.y;
  const int q0  = blockIdx.x * QT;
  const int l   = tid & 63;
  const int w   = tid >> 6;
  const int lm  = l & 15;
  const int lg  = l >> 4;

  const f16* pwq = pw;                  // frag(nt,kt) at ((nt*6+kt)<<9)
  const f16* pwk = pw + 144 * 512;
  const f16* pwv = pw + 264 * 512;
  const f16* pwo = pw + 384 * 512;

  // ---- S1: idx/offset/mask (64 thr) + LayerNorm -> fp16 rows of s_f16 ----
  if (tid < NJ) {
    const int j  = tid;
    const int q  = q0 + (j >> 3);
    const int id = idx_ws[((size_t)b * HW_ + q) * K_ + (j & 7)];
    s_idx[j] = id;
    const float ax = img_uv[id * 2], ay = img_uv[id * 2 + 1];
    const float bx = img_uv[q * 2],  by = img_uv[q * 2 + 1];
    s_offx[j] = ax - bx; s_offy[j] = ay - by;
    const double dox = (double)ax - (double)bx;
    const double doy = (double)ay - (double)by;
    s_mask[j] = (dox * dox + doy * doy <= 0.010000000000000002) ? 1.f : 0.f;
  }
  {
    // zero alias rows 8..15 so Q-MFMA A-fragment rows 8..15 are defined
    unsigned* z = (unsigned*)(s_f16 + 8 * AST);
    for (int o = tid; o < 4 * AST; o += 256) z[o] = 0u;   // 8 rows * AST/2 uints
  }
  {
    const int r  = ((tid >> 6) << 1) | ((tid >> 5) & 1);
    const int sl = tid & 31;
    const float* row = feat_2d + ((size_t)b * HW_ + q0 + r) * IMGD;
    float x[6]; float sum = 0.f, ssq = 0.f;
#pragma unroll
    for (int i = 0; i < 6; ++i) { x[i] = row[sl + 32 * i]; sum += x[i]; ssq += x[i] * x[i]; }
#pragma unroll
    for (int m = 16; m >= 1; m >>= 1) { sum += __shfl_xor(sum, m); ssq += __shfl_xor(ssq, m); }
    const float mu = sum * (1.f / 192.f);
    float var = ssq * (1.f / 192.f) - mu * mu;
    var = fmaxf(var, 0.f);
    const float rstd = rsqrtf(var + 1e-5f);
#pragma unroll
    for (int i = 0; i < 6; ++i) {
      const int c = sl + 32 * i;
      s_f16[r * AST + c] = (f16)((x[i] - mu) * rstd * ln_gamma[c]);
    }
  }
  __syncthreads();

  // ---- S2: X-stage loads (early), Q-MFMA, X convert/write, pos-emb --------
  const int jX = tid >> 2, tsub = tid & 3;
  float4 xf[8];
  {
    const float4* f4 = reinterpret_cast<const float4*>(
        feat_3d + ((size_t)b * HW_ + s_idx[jX]) * PTD) + tsub * 8;
#pragma unroll
    for (int i = 0; i < 8; ++i) xf[i] = f4[i];
  }
  f32x4 qacc[6];
#pragma unroll
  for (int t = 0; t < 6; ++t) qacc[t] = (f32x4){0.f, 0.f, 0.f, 0.f};
  {
    const f16* ar = s_f16 + lm * AST + lg * 8;
#pragma unroll
    for (int kt = 0; kt < KTQ; ++kt) {
      const f16x8 a = *(const f16x8*)(ar + kt * 32);
#pragma unroll
      for (int t = 0; t < 6; ++t) {
        const int nt = w * 6 + t;
        const f16x8 bf = *(const f16x8*)(pwq + (((nt * 6 + kt) << 6) + l) * 8);
        qacc[t] = __builtin_amdgcn_mfma_f32_16x16x32_f16(a, bf, qacc[t], 0, 0, 0);
      }
    }
  }
  {
    f16* xr = &s_X[jX][tsub * 32];
#pragma unroll
    for (int i = 0; i < 8; ++i) {
      xr[i * 4 + 0] = (f16)xf[i].x; xr[i * 4 + 1] = (f16)xf[i].y;
      xr[i * 4 + 2] = (f16)xf[i].z; xr[i * 4 + 3] = (f16)xf[i].w;
    }
    if (tsub == 0) {
      const float ox = s_offx[jX], oy = s_offy[jX];
      f16* xp = &s_X[jX][PTD];
#pragma unroll
      for (int m = 0; m < 6; ++m) {
        const float fr = (float)(1 << m);
        float sx, cx, sy, cy;
        sincosf(ox * fr, &sx, &cx);
        sincosf(oy * fr, &sy, &cy);
        xp[m] = (f16)sx; xp[6 + m] = (f16)sy;
        xp[12 + m] = (f16)cx; xp[18 + m] = (f16)cy;
      }
      xp[24] = (f16)ox; xp[25] = (f16)oy;
#pragma unroll
      for (int m = 26; m < 32; ++m) xp[m] = (f16)0.f;   // CRITICAL: pad k=154..159
    }
  }
  __syncthreads();

  // ---- S2b: write q (fp32) rows 0..7 — overwrites LN bytes (all reads done)
  if (lg < 2) {
#pragma unroll
    for (int t = 0; t < 6; ++t) {
#pragma unroll
      for (int reg = 0; reg < 4; ++reg) {
        s_regA[(lg * 4 + reg) * AST + (w * 6 + t) * 16 + lm] = qacc[t][reg];
      }
    }
  }
  __syncthreads();

  // ---- S3: q norms (48 thr) ----------------------------------------------
  if (tid < QT * NH_) {
    const int r = tid / NH_, h = tid % NH_;
    const float* v = s_regA + r * AST + h * DH_;
    float ss = 0.f;
#pragma unroll
    for (int d = 0; d < DH_; ++d) ss += v[d] * v[d];
    s_norm[tid] = fmaxf(sqrtf(ss), 1e-12f);
  }
  __syncthreads();

  // ---- S4: scale q in place ----------------------------------------------
  {
    const int r  = tid >> 5;
    const int c0 = (tid & 31) * 12;
#pragma unroll
    for (int i = 0; i < 12; ++i) {
      const int c = c0 + i;
      const float n = s_norm[r * NH_ + (c >> 6)];
      s_regA[r * AST + c] *= (8.f / n) * q_gamma[c];
    }
  }
  __syncthreads();

  // ---- S5: K-MFMA (wave owns kv rows 16w..16w+15) + RMSNorm + scores ------
  {
    const f16* xh = &s_X[16 * w + lm][lg * 8];
    f16x8 ax[KTK];
#pragma unroll
    for (int kt = 0; kt < KTK; ++kt) ax[kt] = *(const f16x8*)(xh + kt * 32);
    const int rq = 2 * w + (lg >> 1);
    for (int h = 0; h < NH_; ++h) {
      f32x4 kacc[4];
#pragma unroll
      for (int t = 0; t < 4; ++t) kacc[t] = (f32x4){0.f, 0.f, 0.f, 0.f};
#pragma unroll
      for (int kt = 0; kt < KTK; ++kt) {
#pragma unroll
        for (int t = 0; t < 4; ++t) {
          const int nt = h * 4 + t;
          const f16x8 bf = *(const f16x8*)(pwk + (((nt * 5 + kt) << 6) + l) * 8);
          kacc[t] = __builtin_amdgcn_mfma_f32_16x16x32_f16(ax[kt], bf, kacc[t], 0, 0, 0);
        }
      }
      float ss[4], sc[4];
#pragma unroll
      for (int reg = 0; reg < 4; ++reg) { ss[reg] = 0.f; sc[reg] = 0.f; }
#pragma unroll
      for (int t = 0; t < 4; ++t) {
        const int n = h * DH_ + t * 16 + lm;
        const float qg = s_regA[rq * AST + n] * k_gamma[n];
#pragma unroll
        for (int reg = 0; reg < 4; ++reg) {
          const float v = kacc[t][reg];
          ss[reg] += v * v;
          sc[reg] += v * qg;
        }
      }
#pragma unroll
      for (int m = 1; m < 16; m <<= 1) {
#pragma unroll
        for (int reg = 0; reg < 4; ++reg) {
          ss[reg] += __shfl_xor(ss[reg], m);
          sc[reg] += __shfl_xor(sc[reg], m);
        }
      }
      if (lm == 0) {
#pragma unroll
        for (int reg = 0; reg < 4; ++reg) {
          const float nn = fmaxf(sqrtf(ss[reg]), 1e-12f);
          s_scores[16 * w + (lg << 2) + reg][h] = (8.f / nn) * sc[reg];
        }
      }
    }
  }
  __syncthreads();

  // ---- S6: masked softmax (48 thr) ----------------------------------------
  if (tid < QT * NH_) {
    const int r = tid / NH_, h = tid % NH_;
    float s[K_]; float mx = -1e38f;
#pragma unroll
    for (int k = 0; k < K_; ++k) {
      float v = s_scores[r * K_ + k][h];
      if (s_mask[r * K_ + k] == 0.f) v = -1e30f;
      s[k] = v; mx = fmaxf(mx, v);
    }
    float sum = 0.f;
#pragma unroll
    for (int k = 0; k < K_; ++k) { const float pp = expf(s[k] - mx); s[k] = pp; sum += pp; }
    const float inv = 1.f / sum;
#pragma unroll
    for (int k = 0; k < K_; ++k) s_attn[r][h][k] = s[k] * inv;
  }
  __syncthreads();

  // ---- S7: V-MFMA over ALL 64 kv rows + in-register attn-weighted reduce --
  // attn_out (fp16) overwrites s_f16 rows 0..7 (q is dead); rows 8..15 zeroed
  // (they hold fp32-q upper bytes = potential NaN patterns for S8's A rows).
  {
    unsigned* z = (unsigned*)(s_f16 + 8 * AST);
    for (int o = tid; o < 4 * AST; o += 256) z[o] = 0u;
  }
  {
    const int k0 = (lg & 1) * 4;
#pragma unroll
    for (int mt = 0; mt < 4; ++mt) {
      const f16* xh = &s_X[16 * mt + lm][lg * 8];
      f16x8 av[KTK];
#pragma unroll
      for (int kt = 0; kt < KTK; ++kt) av[kt] = *(const f16x8*)(xh + kt * 32);
      const int qrow = 2 * mt + (lg >> 1);
#pragma unroll
      for (int t = 0; t < 6; ++t) {
        const int nt = w * 6 + t;
        const int h  = nt >> 2;
        f32x4 c = (f32x4){0.f, 0.f, 0.f, 0.f};
#pragma unroll
        for (int kt = 0; kt < KTK; ++kt) {
          const f16x8 bf = *(const f16x8*)(pwv + (((nt * 5 + kt) << 6) + l) * 8);
          c = __builtin_amdgcn_mfma_f32_16x16x32_f16(av[kt], bf, c, 0, 0, 0);
        }
        const float4 at = *(const float4*)&s_attn[qrow][h][k0];
        float p = at.x * c[0] + at.y * c[1] + at.z * c[2] + at.w * c[3];
        p += __shfl_xor(p, 16);
        if ((lg & 1) == 0) s_f16[qrow * AST + nt * 16 + lm] = (f16)p;
      }
    }
  }
  __syncthreads();

  // ---- S8: out-projection fp16 MFMA ---------------------------------------
  {
    f32x4 oacc[6];
#pragma unroll
    for (int t = 0; t < 6; ++t) oacc[t] = (f32x4){0.f, 0.f, 0.f, 0.f};
    const f16* ar = s_f16 + lm * AST + lg * 8;
#pragma unroll
    for (int kt = 0; kt < KTO; ++kt) {
      const f16x8 a = *(const f16x8*)(ar + kt * 32);
#pragma unroll
      for (int t = 0; t < 6; ++t) {
        const int nt = w * 6 + t;
        const f16x8 bf = *(const f16x8*)(pwo + (((nt * 12 + kt) << 6) + l) * 8);
        oacc[t] = __builtin_amdgcn_mfma_f32_16x16x32_f16(a, bf, oacc[t], 0, 0, 0);
      }
    }
    if (lg < 2) {
      float* orow0 = out + ((size_t)b * HW_ + q0) * INNER;
#pragma unroll
      for (int reg = 0; reg < 4; ++reg) {
        const int m = lg * 4 + reg;
#pragma unroll
        for (int t = 0; t < 6; ++t) {
          orow0[(size_t)m * INNER + (w * 6 + t) * 16 + lm] = oacc[t][reg];
        }
      }
    }
  }
}

// ---------------------------------------------------------------------------
extern "C" void kernel_launch(void* const* d_in, const int* in_sizes, int n_in,
                              void* d_out, int out_size, void* d_ws, size_t ws_size,
                              hipStream_t stream) {
  (void)in_sizes; (void)n_in; (void)out_size; (void)ws_size;
  const float* feat_2d = (const float*)d_in[0];
  const float* feat_3d = (const float*)d_in[1];
  const float* proj_uv = (const float*)d_in[2];
  const float* img_uv  = (const float*)d_in[3];
  const float* ln_g    = (const float*)d_in[4];
  const float* q_g     = (const float*)d_in[5];
  const float* k_g     = (const float*)d_in[6];
  const float* Wq      = (const float*)d_in[7];
  const float* Wkv     = (const float*)d_in[8];
  const float* Wout    = (const float*)d_in[9];
  float* out = (float*)d_out;

  // ws: idx (614400 B, 16B-aligned) | packed fp16 weights (672*512*2 B)
  int* idx_ws = (int*)d_ws;
  f16* pw = (f16*)((char*)d_ws + 614400);

  pack_kernel<<<dim3(1344), 256, 0, stream>>>(Wq, Wkv, Wout, pw);
  knn_kernel<<<dim3(B_ * HW_ / 8), 256, 0, stream>>>(proj_uv, img_uv, idx_ws);
  fused_kernel<<<dim3(HW_ / QT, B_), 256, 0, stream>>>(
      feat_2d, feat_3d, img_uv, ln_g, q_g, k_g, pw, idx_ws, out);
}

// Round 8
// 316.224 us; speedup vs baseline: 4.3880x; 1.0132x over previous
//
#include <hip/hip_runtime.h>
#include <math.h>

#define B_    4
#define HW_   4800
#define K_    8
#define IMGD  192
#define PTD   128
#define NH_   6
#define DH_   64
#define INNER 384
#define KVIN  154
#define QT    8
#define NJ    64
#define XBS   168    // fp16 X row stride (336B -> 8-way bank spread)
#define AST   392    // alias stride: f16 rows [16][AST], fp32 q rows [8][AST floats]
#define KTQ   6      // Q-proj k-steps (192)
#define KTK   5      // K/V k-steps (154 -> 160, zero-padded both sides)
#define KTO   12     // out-proj k-steps (384)

typedef _Float16 f16;
typedef __attribute__((ext_vector_type(8))) _Float16 f16x8;
typedef __attribute__((ext_vector_type(4))) float f32x4;

// ---------------------------------------------------------------------------
// Kernel 0: pack all weights into fp16 MFMA fragment order.
// frag element (l, j):  k = kt*32 + (l>>4)*8 + j,  n = nt*16 + (l&15)
// ---------------------------------------------------------------------------
__global__ __launch_bounds__(256) void pack_kernel(
    const float* __restrict__ Wq, const float* __restrict__ Wkv,
    const float* __restrict__ Wout, f16* __restrict__ pw)
{
  const int e = blockIdx.x * 256 + threadIdx.x;     // 672*512 = 344064 total
  if (e >= 672 * 512) return;
  const int f = e >> 9, r = e & 511, l = r >> 3, j = r & 7;
  const int lm = l & 15, kin = (l >> 4) * 8 + j;
  float v;
  if (f < 144) {                                    // Wq [192][384]
    const int nt = f / 6, kt = f % 6;
    v = Wq[(size_t)(kt * 32 + kin) * INNER + nt * 16 + lm];
  } else if (f < 264) {                             // Wk = Wkv[:, :384]
    const int g = f - 144, nt = g / 5, kt = g % 5, k = kt * 32 + kin;
    v = (k < KVIN) ? Wkv[(size_t)k * (2 * INNER) + nt * 16 + lm] : 0.f;
  } else if (f < 384) {                             // Wv = Wkv[:, 384:]
    const int g = f - 264, nt = g / 5, kt = g % 5, k = kt * 32 + kin;
    v = (k < KVIN) ? Wkv[(size_t)k * (2 * INNER) + INNER + nt * 16 + lm] : 0.f;
  } else {                                          // Wout [384][384]
    const int g = f - 384, nt = g / 12, kt = g % 12;
    v = Wout[(size_t)(kt * 32 + kin) * INNER + nt * 16 + lm];
  }
  pw[e] = (f16)v;
}

// ---------------------------------------------------------------------------
// Kernel 1: brute-force kNN. 4 queries per wave (4 independent chains amortize
// LDS reads + loop overhead). Distance = verified r3 BLAS-f32 form. Per-lane
// scan order unchanged (n = lane + 64*i) so tie semantics are preserved.
// ---------------------------------------------------------------------------
#define KNN_INIT(d, ind)                                                      \
  _Pragma("unroll") for (int s = 0; s < K_; ++s) { d[s] = 3.4e38f; ind[s] = 0x7fffffff; }

#define KNN_INSERT(dd, n, dist, ind)                                          \
  if (dd < dist[K_ - 1]) {                                                    \
    bool placed = false;                                                      \
    _Pragma("unroll") for (int s = K_ - 1; s >= 1; --s) {                     \
      if (!placed) {                                                          \
        if (dd < dist[s - 1]) { dist[s] = dist[s - 1]; ind[s] = ind[s - 1]; } \
        else                  { dist[s] = dd; ind[s] = n; placed = true; }    \
      }                                                                       \
    }                                                                         \
    if (!placed) { dist[0] = dd; ind[0] = n; }                                \
  }

#define KNN_MERGE(dist, ind, qidx)                                            \
  _Pragma("unroll") for (int r = 0; r < K_; ++r) {                            \
    float hd = dist[0]; int hi = ind[0];                                      \
    float bd = hd; int bi = hi;                                               \
    _Pragma("unroll") for (int m = 1; m < 64; m <<= 1) {                      \
      float od = __shfl_xor(bd, m); int oi = __shfl_xor(bi, m);               \
      if (od < bd || (od == bd && oi < bi)) { bd = od; bi = oi; }             \
    }                                                                         \
    const bool won = (hd == bd && hi == bi);                                  \
    _Pragma("unroll") for (int s = 0; s < K_ - 1; ++s) {                      \
      dist[s] = won ? dist[s + 1] : dist[s];                                  \
      ind[s]  = won ? ind[s + 1]  : ind[s];                                   \
    }                                                                         \
    dist[K_ - 1] = won ? 3.4e38f : dist[K_ - 1];                              \
    ind[K_ - 1]  = won ? 0x7fffffff : ind[K_ - 1];                            \
    if (lane == r) idx_out[((size_t)b * HW_ + (qidx)) * K_ + r] = bi;         \
  }

__global__ __launch_bounds__(256) void knn_kernel(
    const float* __restrict__ proj_uv,
    const float* __restrict__ img_uv,
    int* __restrict__ idx_out)
{
#pragma clang fp contract(off)
  __shared__ float2 s_p[HW_];                      // 38.4KB -> 4 blocks/CU

  const int tid  = threadIdx.x;
  const int wave = tid >> 6;
  const int lane = tid & 63;
  const int blk  = blockIdx.x;                     // 0..1199
  const int b    = blk / (HW_ / 16);
  const int q0   = (blk % (HW_ / 16)) * 16 + wave * 4;

  const float2* pv = reinterpret_cast<const float2*>(proj_uv + (size_t)b * HW_ * 2);
  for (int i = tid; i < HW_; i += 256) s_p[i] = pv[i];
  __syncthreads();

  float qx[4], qy[4], sqq[4];
#pragma unroll
  for (int c = 0; c < 4; ++c) {
    qx[c] = img_uv[(q0 + c) * 2];
    qy[c] = img_uv[(q0 + c) * 2 + 1];
    sqq[c] = qx[c] * qx[c] + qy[c] * qy[c];        // square-then-sum, no fma
  }

  float dA[K_], dB[K_], dC[K_], dD[K_];
  int   iA[K_], iB[K_], iC[K_], iD[K_];
  KNN_INIT(dA, iA); KNN_INIT(dB, iB); KNN_INIT(dC, iC); KNN_INIT(dD, iD);

  for (int n = lane; n < HW_; n += 64) {
    const float2 p = s_p[n];
    const float sqp = p.x * p.x + p.y * p.y;          // f32 no fma (pragma)
    const float t0 = fmaf(qy[0], p.y, qx[0] * p.x);   // BLAS K=2 fma form
    const float e0 = (sqq[0] + sqp) - 2.0f * t0;
    KNN_INSERT(e0, n, dA, iA);
    const float t1 = fmaf(qy[1], p.y, qx[1] * p.x);
    const float e1 = (sqq[1] + sqp) - 2.0f * t1;
    KNN_INSERT(e1, n, dB, iB);
    const float t2 = fmaf(qy[2], p.y, qx[2] * p.x);
    const float e2 = (sqq[2] + sqp) - 2.0f * t2;
    KNN_INSERT(e2, n, dC, iC);
    const float t3 = fmaf(qy[3], p.y, qx[3] * p.x);
    const float e3 = (sqq[3] + sqp) - 2.0f * t3;
    KNN_INSERT(e3, n, dD, iD);
  }

  KNN_MERGE(dA, iA, q0 + 0);
  KNN_MERGE(dB, iB, q0 + 1);
  KNN_MERGE(dC, iC, q0 + 2);
  KNN_MERGE(dD, iD, q0 + 3);
}

// ---------------------------------------------------------------------------
// Kernel 2: fused fp16-MFMA pipeline. This round: (a) K-phase n-partitioned
// (wave w -> nt = 4h+w) so each K-fragment is read ONCE per block, with
// cross-wave RMSNorm partials via LDS atomicAdd; (b) V-phase fragments
// hoisted to registers (read once, A re-read from LDS); (c) XCD-aware
// blockIdx swizzle for gather L2 locality. NaN hygiene as r7.
// ---------------------------------------------------------------------------
__global__ __launch_bounds__(256, 4) void fused_kernel(
    const float* __restrict__ feat_2d,
    const float* __restrict__ feat_3d,
    const float* __restrict__ img_uv,
    const float* __restrict__ ln_gamma,
    const float* __restrict__ q_gamma,
    const float* __restrict__ k_gamma,
    const f16*   __restrict__ pw,
    const int*   __restrict__ idx_ws,
    float* __restrict__ out)
{
  __shared__ alignas(16) f16   s_X[NJ][XBS];       // 64 kv rows fp16 (21.5KB)
  __shared__ alignas(16) float s_regA[QT * AST];   // q fp32 | alias f16[16][AST]
  __shared__ float s_scores[NJ][NH_];
  __shared__ float s_kss[NJ][NH_];                 // K-RMSNorm partials (atomic)
  __shared__ float s_ksc[NJ][NH_];                 // score partials (atomic)
  __shared__ float s_mask[NJ];
  __shared__ int   s_idx[NJ];
  __shared__ float s_offx[NJ];
  __shared__ float s_offy[NJ];
  __shared__ float s_norm[QT * NH_];

  f16* s_f16 = reinterpret_cast<f16*>(s_regA);     // [16][AST]
  // attn aliases the kss partials (dead after scores are computed)
  float (*s_attn)[NH_][K_] = reinterpret_cast<float (*)[NH_][K_]>(&s_kss[0][0]);

  const int tid = threadIdx.x;
  const int b   = blockIdx.y;
  // XCD-aware bijective swizzle: 600 tiles % 8 XCDs == 0
  const int bx  = (blockIdx.x & 7) * 75 + (blockIdx.x >> 3);
  const int q0  = bx * QT;
  const int l   = tid & 63;
  const int w   = tid >> 6;
  const int lm  = l & 15;
  const int lg  = l >> 4;

  const f16* pwq = pw;
  const f16* pwk = pw + 144 * 512;
  const f16* pwv = pw + 264 * 512;
  const f16* pwo = pw + 384 * 512;

  // ---- S1: idx/offset/mask (64 thr) + zero alias rows 8..15 + LayerNorm ---
  if (tid < NJ) {
    const int j  = tid;
    const int q  = q0 + (j >> 3);
    const int id = idx_ws[((size_t)b * HW_ + q) * K_ + (j & 7)];
    s_idx[j] = id;
    const float ax = img_uv[id * 2], ay = img_uv[id * 2 + 1];
    const float bx2 = img_uv[q * 2], by2 = img_uv[q * 2 + 1];
    s_offx[j] = ax - bx2; s_offy[j] = ay - by2;
    const double dox = (double)ax - (double)bx2;
    const double doy = (double)ay - (double)by2;
    s_mask[j] = (dox * dox + doy * doy <= 0.010000000000000002) ? 1.f : 0.f;
  }
  {
    unsigned* z = (unsigned*)(s_f16 + 8 * AST);
    for (int o = tid; o < 4 * AST; o += 256) z[o] = 0u;
  }
  {
    const int r  = ((tid >> 6) << 1) | ((tid >> 5) & 1);
    const int sl = tid & 31;
    const float* row = feat_2d + ((size_t)b * HW_ + q0 + r) * IMGD;
    float x[6]; float sum = 0.f, ssq = 0.f;
#pragma unroll
    for (int i = 0; i < 6; ++i) { x[i] = row[sl + 32 * i]; sum += x[i]; ssq += x[i] * x[i]; }
#pragma unroll
    for (int m = 16; m >= 1; m >>= 1) { sum += __shfl_xor(sum, m); ssq += __shfl_xor(ssq, m); }
    const float mu = sum * (1.f / 192.f);
    float var = ssq * (1.f / 192.f) - mu * mu;
    var = fmaxf(var, 0.f);
    const float rstd = rsqrtf(var + 1e-5f);
#pragma unroll
    for (int i = 0; i < 6; ++i) {
      const int c = sl + 32 * i;
      s_f16[r * AST + c] = (f16)((x[i] - mu) * rstd * ln_gamma[c]);
    }
  }
  __syncthreads();

  // ---- S2: X-stage loads (early), Q-MFMA, X convert/write, pos-emb --------
  const int jX = tid >> 2, tsub = tid & 3;
  float4 xf[8];
  {
    const float4* f4 = reinterpret_cast<const float4*>(
        feat_3d + ((size_t)b * HW_ + s_idx[jX]) * PTD) + tsub * 8;
#pragma unroll
    for (int i = 0; i < 8; ++i) xf[i] = f4[i];
  }
  f32x4 qacc[6];
#pragma unroll
  for (int t = 0; t < 6; ++t) qacc[t] = (f32x4){0.f, 0.f, 0.f, 0.f};
  {
    const f16* ar = s_f16 + lm * AST + lg * 8;
#pragma unroll
    for (int kt = 0; kt < KTQ; ++kt) {
      const f16x8 a = *(const f16x8*)(ar + kt * 32);
#pragma unroll
      for (int t = 0; t < 6; ++t) {
        const int nt = w * 6 + t;
        const f16x8 bf = *(const f16x8*)(pwq + (((nt * 6 + kt) << 6) + l) * 8);
        qacc[t] = __builtin_amdgcn_mfma_f32_16x16x32_f16(a, bf, qacc[t], 0, 0, 0);
      }
    }
  }
  {
    f16* xr = &s_X[jX][tsub * 32];
#pragma unroll
    for (int i = 0; i < 8; ++i) {
      xr[i * 4 + 0] = (f16)xf[i].x; xr[i * 4 + 1] = (f16)xf[i].y;
      xr[i * 4 + 2] = (f16)xf[i].z; xr[i * 4 + 3] = (f16)xf[i].w;
    }
    if (tsub == 0) {
      const float ox = s_offx[jX], oy = s_offy[jX];
      f16* xp = &s_X[jX][PTD];
#pragma unroll
      for (int m = 0; m < 6; ++m) {
        const float fr = (float)(1 << m);
        float sx, cx, sy, cy;
        sincosf(ox * fr, &sx, &cx);
        sincosf(oy * fr, &sy, &cy);
        xp[m] = (f16)sx; xp[6 + m] = (f16)sy;
        xp[12 + m] = (f16)cx; xp[18 + m] = (f16)cy;
      }
      xp[24] = (f16)ox; xp[25] = (f16)oy;
#pragma unroll
      for (int m = 26; m < 32; ++m) xp[m] = (f16)0.f;   // pad k=154..159
    }
  }
  __syncthreads();

  // ---- S2b: write q (fp32) rows 0..7 --------------------------------------
  if (lg < 2) {
#pragma unroll
    for (int t = 0; t < 6; ++t) {
#pragma unroll
      for (int reg = 0; reg < 4; ++reg) {
        s_regA[(lg * 4 + reg) * AST + (w * 6 + t) * 16 + lm] = qacc[t][reg];
      }
    }
  }
  __syncthreads();

  // ---- S3: q norms (48 thr) -----------------------------------------------
  if (tid < QT * NH_) {
    const int r = tid / NH_, h = tid % NH_;
    const float* v = s_regA + r * AST + h * DH_;
    float ss = 0.f;
#pragma unroll
    for (int d = 0; d < DH_; ++d) ss += v[d] * v[d];
    s_norm[tid] = fmaxf(sqrtf(ss), 1e-12f);
  }
  __syncthreads();

  // ---- S4: scale q in place + zero K partials -----------------------------
  {
    const int r  = tid >> 5;
    const int c0 = (tid & 31) * 12;
#pragma unroll
    for (int i = 0; i < 12; ++i) {
      const int c = c0 + i;
      const float n = s_norm[r * NH_ + (c >> 6)];
      s_regA[r * AST + c] *= (8.f / n) * q_gamma[c];
    }
  }
  for (int o = tid; o < NJ * NH_; o += 256) {
    s_kss[o / NH_][o % NH_] = 0.f;
    s_ksc[o / NH_][o % NH_] = 0.f;
  }
  __syncthreads();

  // ---- S5: K-MFMA n-partitioned: wave w -> nt = 4h + w (one per head),
  //          all 4 row-tiles; fragments read ONCE per block. Per-(row,head)
  //          RMSNorm/score partials accumulated cross-wave via LDS atomics.
  {
    for (int h = 0; h < NH_; ++h) {
      const int nt  = h * 4 + w;
      const int col = nt * 16 + lm;
      f16x8 bf[KTK];
#pragma unroll
      for (int kt = 0; kt < KTK; ++kt)
        bf[kt] = *(const f16x8*)(pwk + (((nt * KTK + kt) << 6) + l) * 8);
      const float kg = k_gamma[col];
#pragma unroll
      for (int mt = 0; mt < 4; ++mt) {
        const f16* xh = &s_X[16 * mt + lm][lg * 8];
        f32x4 c = (f32x4){0.f, 0.f, 0.f, 0.f};
#pragma unroll
        for (int kt = 0; kt < KTK; ++kt)
          c = __builtin_amdgcn_mfma_f32_16x16x32_f16(
              *(const f16x8*)(xh + kt * 32), bf[kt], c, 0, 0, 0);
        const int rq = 2 * mt + (lg >> 1);
        const float qg = s_regA[rq * AST + col] * kg;
        float ss[4], sc[4];
#pragma unroll
        for (int reg = 0; reg < 4; ++reg) {
          const float v = c[reg];
          ss[reg] = v * v; sc[reg] = v * qg;
        }
#pragma unroll
        for (int m = 1; m < 16; m <<= 1) {
#pragma unroll
          for (int reg = 0; reg < 4; ++reg) {
            ss[reg] += __shfl_xor(ss[reg], m);
            sc[reg] += __shfl_xor(sc[reg], m);
          }
        }
        if (lm == 0) {
#pragma unroll
          for (int reg = 0; reg < 4; ++reg) {
            const int row = 16 * mt + 4 * lg + reg;
            atomicAdd(&s_kss[row][h], ss[reg]);
            atomicAdd(&s_ksc[row][h], sc[reg]);
          }
        }
      }
    }
  }
  __syncthreads();
  // ---- S5b: finalize scores from partials (384 tasks) ---------------------
  for (int o = tid; o < NJ * NH_; o += 256) {
    const int row = o / NH_, h = o - row * NH_;
    const float nn = fmaxf(sqrtf(s_kss[row][h]), 1e-12f);
    s_scores[row][h] = (8.f / nn) * s_ksc[row][h];
  }
  __syncthreads();

  // ---- S6: masked softmax (48 thr) — attn aliases kss (dead) --------------
  if (tid < QT * NH_) {
    const int r = tid / NH_, h = tid % NH_;
    float s[K_]; float mx = -1e38f;
#pragma unroll
    for (int k = 0; k < K_; ++k) {
      float v = s_scores[r * K_ + k][h];
      if (s_mask[r * K_ + k] == 0.f) v = -1e30f;
      s[k] = v; mx = fmaxf(mx, v);
    }
    float sum = 0.f;
#pragma unroll
    for (int k = 0; k < K_; ++k) { const float pp = expf(s[k] - mx); s[k] = pp; sum += pp; }
    const float inv = 1.f / sum;
#pragma unroll
    for (int k = 0; k < K_; ++k) s_attn[r][h][k] = s[k] * inv;
  }
  __syncthreads();

  // ---- S7: V-MFMA with hoisted fragments + in-register attn reduce --------
  // attn_out (fp16) overwrites s_f16 rows 0..7 (q dead); zero rows 8..15.
  {
    unsigned* z = (unsigned*)(s_f16 + 8 * AST);
    for (int o = tid; o < 4 * AST; o += 256) z[o] = 0u;
  }
  {
    const int k0 = (lg & 1) * 4;
#pragma unroll
    for (int t = 0; t < 6; ++t) {
      const int nt = w * 6 + t;
      const int h  = nt >> 2;
      f16x8 bf[KTK];
#pragma unroll
      for (int kt = 0; kt < KTK; ++kt)
        bf[kt] = *(const f16x8*)(pwv + (((nt * KTK + kt) << 6) + l) * 8);
#pragma unroll
      for (int mt = 0; mt < 4; ++mt) {
        const f16* xh = &s_X[16 * mt + lm][lg * 8];
        f32x4 c = (f32x4){0.f, 0.f, 0.f, 0.f};
#pragma unroll
        for (int kt = 0; kt < KTK; ++kt)
          c = __builtin_amdgcn_mfma_f32_16x16x32_f16(
              *(const f16x8*)(xh + kt * 32), bf[kt], c, 0, 0, 0);
        const int qrow = 2 * mt + (lg >> 1);
        const float4 at = *(const float4*)&s_attn[qrow][h][k0];
        float p = at.x * c[0] + at.y * c[1] + at.z * c[2] + at.w * c[3];
        p += __shfl_xor(p, 16);
        if ((lg & 1) == 0) s_f16[qrow * AST + nt * 16 + lm] = (f16)p;
      }
    }
  }
  __syncthreads();

  // ---- S8: out-projection fp16 MFMA ---------------------------------------
  {
    f32x4 oacc[6];
#pragma unroll
    for (int t = 0; t < 6; ++t) oacc[t] = (f32x4){0.f, 0.f, 0.f, 0.f};
    const f16* ar = s_f16 + lm * AST + lg * 8;
#pragma unroll
    for (int kt = 0; kt < KTO; ++kt) {
      const f16x8 a = *(const f16x8*)(ar + kt * 32);
#pragma unroll
      for (int t = 0; t < 6; ++t) {
        const int nt = w * 6 + t;
        const f16x8 bf = *(const f16x8*)(pwo + (((nt * 12 + kt) << 6) + l) * 8);
        oacc[t] = __builtin_amdgcn_mfma_f32_16x16x32_f16(a, bf, oacc[t], 0, 0, 0);
      }
    }
    if (lg < 2) {
      float* orow0 = out + ((size_t)b * HW_ + q0) * INNER;
#pragma unroll
      for (int reg = 0; reg < 4; ++reg) {
        const int m = lg * 4 + reg;
#pragma unroll
        for (int t = 0; t < 6; ++t) {
          orow0[(size_t)m * INNER + (w * 6 + t) * 16 + lm] = oacc[t][reg];
        }
      }
    }
  }
}

// ---------------------------------------------------------------------------
extern "C" void kernel_launch(void* const* d_in, const int* in_sizes, int n_in,
                              void* d_out, int out_size, void* d_ws, size_t ws_size,
                              hipStream_t stream) {
  (void)in_sizes; (void)n_in; (void)out_size; (void)ws_size;
  const float* feat_2d = (const float*)d_in[0];
  const float* feat_3d = (const float*)d_in[1];
  const float* proj_uv = (const float*)d_in[2];
  const float* img_uv  = (const float*)d_in[3];
  const float* ln_g    = (const float*)d_in[4];
  const float* q_g     = (const float*)d_in[5];
  const float* k_g     = (const float*)d_in[6];
  const float* Wq      = (const float*)d_in[7];
  const float* Wkv     = (const float*)d_in[8];
  const float* Wout    = (const float*)d_in[9];
  float* out = (float*)d_out;

  // ws: idx (614400 B, 16B-aligned) | packed fp16 weights (672*512*2 B)
  int* idx_ws = (int*)d_ws;
  f16* pw = (f16*)((char*)d_ws + 614400);

  pack_kernel<<<dim3(1344), 256, 0, stream>>>(Wq, Wkv, Wout, pw);
  knn_kernel<<<dim3(B_ * HW_ / 16), 256, 0, stream>>>(proj_uv, img_uv, idx_ws);
  fused_kernel<<<dim3(HW_ / QT, B_), 256, 0, stream>>>(
      feat_2d, feat_3d, img_uv, ln_g, q_g, k_g, pw, idx_ws, out);
}